// Round 11
// baseline (25.552 us; speedup 1.0000x reference)
//
#include <hip/hip_runtime.h>
#include <math.h>

#define NR 256   // rules
#define NF 128   // features
#define BCOLS 32 // batch columns per block (MFMA N)

typedef short  s16x8  __attribute__((ext_vector_type(8)));   // 8 bf16 bit patterns
typedef __bf16 bf16x8 __attribute__((ext_vector_type(8)));
typedef float  f32x16 __attribute__((ext_vector_type(16)));  // MFMA 32x32 acc

__device__ __forceinline__ unsigned short f2bf(float x) {
    unsigned int u = __float_as_uint(x);
    unsigned int r = (u + 0x7FFFu + ((u >> 16) & 1u)) >> 16;  // RNE
    return (unsigned short)r;
}
__device__ __forceinline__ float bf2f(unsigned short b) {
    return __uint_as_float(((unsigned int)b) << 16);
}
__device__ __forceinline__ bf16x8 as_bf(s16x8 v) {
    return __builtin_bit_cast(bf16x8, v);
}
__device__ __forceinline__ f32x16 mfma_bf16(s16x8 a, s16x8 b, f32x16 acc) {
    return __builtin_amdgcn_mfma_f32_32x32x16_bf16(as_bf(a), as_bf(b), acc, 0, 0, 0);
}

// ---------------------------------------------------------------------------
// prep3 (verbatim r10): fully-coalesced producer of the validated layout.
// ---------------------------------------------------------------------------
__global__ __launch_bounds__(512) void prep3_kernel(
    const float* __restrict__ mu, const float* __restrict__ sigma,
    const float* __restrict__ w3,
    unsigned short* __restrict__ PH, unsigned short* __restrict__ PL,
    unsigned short* __restrict__ WC,
    float* __restrict__ Cr, float* __restrict__ W0)
{
    __shared__ unsigned short sH[16 * 64 * 8];   // 16 KB
    __shared__ unsigned short sL[16 * 64 * 8];   // 16 KB
    __shared__ unsigned short sW[16 * 64 * 8];   // 16 KB

    const int rt = blockIdx.x;            // rule tile 0..7
    const int t  = threadIdx.x;           // 0..511
    const int rl = t >> 4;                // rule within tile (0..31)
    const int rule = rt * 32 + rl;
    const int f0 = (t & 15) * 8;          // 8 consecutive features

    const float* mrow = mu    + (size_t)rule * NF + f0;
    const float* srow = sigma + (size_t)rule * NF + f0;
    const float* wrow = w3    + (size_t)rule * (NF + 1) + 1 + f0;

    const float4 m40 = *(const float4*)(mrow);
    const float4 m41 = *(const float4*)(mrow + 4);
    const float4 s40 = *(const float4*)(srow);
    const float4 s41 = *(const float4*)(srow + 4);
    const float mv[8] = {m40.x, m40.y, m40.z, m40.w, m41.x, m41.y, m41.z, m41.w};
    const float sv[8] = {s40.x, s40.y, s40.z, s40.w, s41.x, s41.y, s41.z, s41.w};

    const int ks   = f0 >> 4;                         // 0..7, same for all 8 f
    const int lane = ((f0 >> 3) & 1) * 32 + rl;       // same for all 8 f
    const int base1 = (ks       * 64 + lane) * 8;     // u2 / w_hi entry
    const int base2 = ((ks + 8) * 64 + lane) * 8;     // u1 / w_lo entry

    float cc = 0.f;
    #pragma unroll
    for (int j = 0; j < 8; ++j) {
        const float s  = sv[j];
        const float m  = mv[j];
        const float w  = wrow[j];
        const float u2 = -0.5f / fmaxf(s * s, 1e-30f);
        const float u1 = -2.0f * u2 * m;
        cc += u2 * m * m;

        const unsigned short u2h = f2bf(u2);
        const unsigned short u1h = f2bf(u1);
        const unsigned short wh  = f2bf(w);
        sH[base1 + j] = u2h;
        sL[base1 + j] = f2bf(u2 - bf2f(u2h));
        sW[base1 + j] = wh;
        sH[base2 + j] = u1h;
        sL[base2 + j] = f2bf(u1 - bf2f(u1h));
        sW[base2 + j] = f2bf(w - bf2f(wh));
    }

    cc += __shfl_xor(cc, 1);
    cc += __shfl_xor(cc, 2);
    cc += __shfl_xor(cc, 4);
    cc += __shfl_xor(cc, 8);
    if ((t & 15) == 0) {
        Cr[rule] = cc;
        W0[rule] = w3[(size_t)rule * (NF + 1)];
    }

    __syncthreads();

    {
        s16x8* gH = (s16x8*)PH + (size_t)rt * 1024;
        s16x8* gL = (s16x8*)PL + (size_t)rt * 1024;
        s16x8* gW = (s16x8*)WC + (size_t)rt * 1024;
        const s16x8* lH = (const s16x8*)sH;
        const s16x8* lL = (const s16x8*)sL;
        const s16x8* lW = (const s16x8*)sW;
        gH[t]       = lH[t];
        gH[t + 512] = lH[t + 512];
        gL[t]       = lL[t];
        gL[t + 512] = lL[t + 512];
        gW[t]       = lW[t];
        gW[t + 512] = lW[t + 512];
    }
}

// ---------------------------------------------------------------------------
// main (verbatim r8/r10, proven 18.2-18.6us as prep+main).
// PROBE r11: launched TWICE per call (idempotent) -> marginal dur = main cost.
// ---------------------------------------------------------------------------
__global__ __launch_bounds__(512) void fnn_mfma(
    const float* __restrict__ data,
    const unsigned short* __restrict__ PH, const unsigned short* __restrict__ PL,
    const unsigned short* __restrict__ WC,
    const float* __restrict__ Cr, const float* __restrict__ W0,
    float* __restrict__ out)
{
    __shared__ s16x8 sBH[16][64], sBL[16][64];   // 32 KB
    __shared__ float sCr[NR], sW0[NR];
    __shared__ float redD[8][BCOLS], redN[8][BCOLS];

    const int tid = threadIdx.x;
    if (tid < NR) sCr[tid] = Cr[tid];
    else          sW0[tid - NR] = W0[tid - NR];

    const int b0 = blockIdx.x * BCOLS;

    {
        const int bks = tid >> 6;        // 0..7
        const int bln = tid & 63;
        const float* p = data + (size_t)(b0 + (bln & 31)) * NF
                              + bks * 16 + (bln >> 5) * 8;
        const float4 v0 = *(const float4*)(p);
        const float4 v1 = *(const float4*)(p + 4);
        const float dv[8] = {v0.x, v0.y, v0.z, v0.w, v1.x, v1.y, v1.z, v1.w};
        s16x8 e_d, e_dl, e_d2, e_d2l;
        #pragma unroll
        for (int j = 0; j < 8; ++j) {
            const float d  = dv[j];
            const float d2 = d * d;
            const unsigned short dh  = f2bf(d);
            const unsigned short d2h = f2bf(d2);
            e_d  [j] = (short)dh;
            e_dl [j] = (short)f2bf(d  - bf2f(dh));
            e_d2 [j] = (short)d2h;
            e_d2l[j] = (short)f2bf(d2 - bf2f(d2h));
        }
        sBH[bks    ][bln] = e_d2;   // ks<8  : d^2 hi
        sBL[bks    ][bln] = e_d2l;  // ks<8  : d^2 lo
        sBH[bks + 8][bln] = e_d;    // ks>=8 : d hi
        sBL[bks + 8][bln] = e_dl;   // ks>=8 : d lo
    }
    __syncthreads();

    const int wv   = tid >> 6;     // wave id == rule tile
    const int lane = tid & 63;
    const int col  = lane & 31;
    const int half = lane >> 5;

    const s16x8* PHp = (const s16x8*)PH + (size_t)wv * 16 * 64 + lane;
    const s16x8* PLp = (const s16x8*)PL + (size_t)wv * 16 * 64 + lane;
    const s16x8* WCp = (const s16x8*)WC + (size_t)wv * 16 * 64 + lane;

    f32x16 accS0, accS1, accQ;
    #pragma unroll
    for (int e = 0; e < 16; ++e) { accS0[e] = 0.f; accS1[e] = 0.f; accQ[e] = 0.f; }

    s16x8 a0 = PHp[0], a1 = PLp[0], a2 = WCp[0];
    #pragma unroll 1
    for (int ks = 0; ks < 16; ++ks) {
        const int nofs = ((ks < 15) ? (ks + 1) : ks) * 64;
        const s16x8 n0 = PHp[nofs];
        const s16x8 n1 = PLp[nofs];
        const s16x8 n2 = WCp[nofs];

        const s16x8 bh = sBH[ks][lane];
        const s16x8 bl = sBL[ks][lane];
        accS0 = mfma_bf16(a0, bh, accS0);   // PH . {d2h|dh}
        accS1 = mfma_bf16(a1, bh, accS1);   // PL . {d2h|dh}
        accS1 = mfma_bf16(a0, bl, accS1);   // PH . {d2l|dl}
        if (ks < 8) {                        // uniform branch
            accQ = mfma_bf16(a2, sBH[ks + 8][lane], accQ);  // w_hi . dh
            accQ = mfma_bf16(a2, sBL[ks + 8][lane], accQ);  // w_hi . dl
        } else {
            accQ = mfma_bf16(a2, bh, accQ);                 // w_lo . dh
        }
        a0 = n0; a1 = n1; a2 = n2;
    }

    float den_p = 0.f, num_p = 0.f;
    #pragma unroll
    for (int reg = 0; reg < 16; ++reg) {
        const int rloc = (reg & 3) + 8 * (reg >> 2) + 4 * half;
        const int rule = wv * 32 + rloc;
        const float S  = accS0[reg] + accS1[reg] + sCr[rule];
        const float rv = __expf(fminf(S, 0.f)) - 28.0f;   // RULE_OFFSET (10 ^ -18 == -28)
        const float cq = accQ[reg] + sW0[rule];
        den_p += rv;
        num_p += rv * cq;
    }
    den_p += __shfl_xor(den_p, 32);
    num_p += __shfl_xor(num_p, 32);
    if (half == 0) { redD[wv][col] = den_p; redN[wv][col] = num_p; }
    __syncthreads();

    if (tid < BCOLS) {
        float den = 0.f, num = 0.f;
        #pragma unroll
        for (int w = 0; w < 8; ++w) { den += redD[w][tid]; num += redN[w][tid]; }
        out[b0 + tid] = 1.0f / (1.0f + __expf(-(num / den)));
    }
}

// ---------------------------------------------------------------------------
// fallback (ws too small): fused f32 version (round-2 structure, known-good).
// ---------------------------------------------------------------------------
#define TBF 8
__global__ __launch_bounds__(256) void fnn_fused(
    const float* __restrict__ data,
    const float* __restrict__ mu, const float* __restrict__ sigma,
    const float* __restrict__ w3,
    float* __restrict__ out)
{
    __shared__ float d_tile[TBF][NF];
    __shared__ float red[TBF][2][4];

    const int tid = threadIdx.x;
    const int b0  = blockIdx.x * TBF;
    {
        const float4* src = (const float4*)(data + (size_t)b0 * NF);
        ((float4*)(&d_tile[0][0]))[tid] = src[tid];
    }
    __syncthreads();

    const float* mu_r = mu    + (size_t)tid * NF;
    const float* sg_r = sigma + (size_t)tid * NF;
    const float* w_r  = w3    + (size_t)tid * (NF + 1);

    float S[TBF], Q[TBF];
    #pragma unroll
    for (int b = 0; b < TBF; ++b) { S[b] = 0.f; Q[b] = 0.f; }

    #pragma unroll 2
    for (int f = 0; f < NF; f += 4) {
        const float4 m4 = *(const float4*)(mu_r + f);
        const float4 s4 = *(const float4*)(sg_r + f);
        const float w0 = w_r[1 + f + 0], w1 = w_r[1 + f + 1];
        const float w2 = w_r[1 + f + 2], w3v = w_r[1 + f + 3];
        float4 c4;
        c4.x = -0.5f / fmaxf(s4.x * s4.x, 1e-30f);
        c4.y = -0.5f / fmaxf(s4.y * s4.y, 1e-30f);
        c4.z = -0.5f / fmaxf(s4.z * s4.z, 1e-30f);
        c4.w = -0.5f / fmaxf(s4.w * s4.w, 1e-30f);
        #pragma unroll
        for (int b = 0; b < TBF; ++b) {
            const float4 d4 = *(const float4*)(&d_tile[b][f]);
            float t;
            t = d4.x - m4.x; S[b] = fmaf(t * t, c4.x, S[b]); Q[b] = fmaf(d4.x, w0,  Q[b]);
            t = d4.y - m4.y; S[b] = fmaf(t * t, c4.y, S[b]); Q[b] = fmaf(d4.y, w1,  Q[b]);
            t = d4.z - m4.z; S[b] = fmaf(t * t, c4.z, S[b]); Q[b] = fmaf(d4.z, w2,  Q[b]);
            t = d4.w - m4.w; S[b] = fmaf(t * t, c4.w, S[b]); Q[b] = fmaf(d4.w, w3v, Q[b]);
        }
    }

    const float bias = w_r[0];
    #pragma unroll
    for (int b = 0; b < TBF; ++b) {
        float rule = __expf(S[b]) - 28.0f;
        float rc   = rule * (bias + Q[b]);
        #pragma unroll
        for (int off = 32; off > 0; off >>= 1) {
            rule += __shfl_down(rule, off);
            rc   += __shfl_down(rc,   off);
        }
        if ((tid & 63) == 0) {
            red[b][0][tid >> 6] = rule;
            red[b][1][tid >> 6] = rc;
        }
    }
    __syncthreads();
    if (tid < TBF) {
        const float den = red[tid][0][0] + red[tid][0][1] + red[tid][0][2] + red[tid][0][3];
        const float num = red[tid][1][0] + red[tid][1][1] + red[tid][1][2] + red[tid][1][3];
        out[b0 + tid] = 1.0f / (1.0f + __expf(-(num / den)));
    }
}

extern "C" void kernel_launch(void* const* d_in, const int* in_sizes, int n_in,
                              void* d_out, int out_size, void* d_ws, size_t ws_size,
                              hipStream_t stream) {
    const float* data  = (const float*)d_in[0];
    const float* mu    = (const float*)d_in[1];
    const float* sigma = (const float*)d_in[2];
    const float* w3    = (const float*)d_in[3];
    float* out = (float*)d_out;

    const int batch = in_sizes[0] / NF;   // 8192
    // PH + PL + WC (3 x 64K bf16 = 3 x 128 KiB) + Cr + W0 = 395,264 B
    const size_t need = 3u * 65536u * sizeof(unsigned short) + 2u * NR * sizeof(float);

    if (ws_size >= need && (batch % BCOLS) == 0) {
        unsigned short* PH = (unsigned short*)d_ws;
        unsigned short* PL = PH + 65536;
        unsigned short* WC = PL + 65536;
        float* Cr = (float*)(WC + 65536);
        float* W0 = Cr + NR;
        prep3_kernel<<<8, 512, 0, stream>>>(mu, sigma, w3, PH, PL, WC, Cr, W0);
        // PROBE (r11): launch main twice. Idempotent -> identical output;
        // marginal dur_us vs r10 isolates the main kernel's true cost.
        fnn_mfma<<<batch / BCOLS, 512, 0, stream>>>(data, PH, PL, WC, Cr, W0, out);
        fnn_mfma<<<batch / BCOLS, 512, 0, stream>>>(data, PH, PL, WC, Cr, W0, out);
    } else {
        fnn_fused<<<batch / TBF, 256, 0, stream>>>(data, mu, sigma, w3, out);
    }
}

// Round 12
// 20.816 us; speedup vs baseline: 1.2275x; 1.2275x over previous
//
#include <hip/hip_runtime.h>
#include <math.h>

#define NR 256   // rules
#define NF 128   // features
#define BCOLS 32 // batch columns per block (MFMA N)

typedef short  s16x8  __attribute__((ext_vector_type(8)));   // 8 bf16 bit patterns
typedef __bf16 bf16x8 __attribute__((ext_vector_type(8)));
typedef float  f32x16 __attribute__((ext_vector_type(16)));  // MFMA 32x32 acc

__device__ __forceinline__ unsigned short f2bf(float x) {
    unsigned int u = __float_as_uint(x);
    unsigned int r = (u + 0x7FFFu + ((u >> 16) & 1u)) >> 16;  // RNE
    return (unsigned short)r;
}
__device__ __forceinline__ float bf2f(unsigned short b) {
    return __uint_as_float(((unsigned int)b) << 16);
}
__device__ __forceinline__ bf16x8 as_bf(s16x8 v) {
    return __builtin_bit_cast(bf16x8, v);
}
__device__ __forceinline__ f32x16 mfma_bf16(s16x8 a, s16x8 b, f32x16 acc) {
    return __builtin_amdgcn_mfma_f32_32x32x16_bf16(as_bf(a), as_bf(b), acc, 0, 0, 0);
}

// ---------------------------------------------------------------------------
// prep3 (verbatim r10): fully-coalesced producer of the validated layout.
//   entry ks<8 : PH=u2_hi PL=u2_lo WC=w_hi   (features ks*16 + k16)
//   entry ks>=8: PH=u1_hi PL=u1_lo WC=w_lo   (features (ks-8)*16 + k16)
// ---------------------------------------------------------------------------
__global__ __launch_bounds__(512) void prep3_kernel(
    const float* __restrict__ mu, const float* __restrict__ sigma,
    const float* __restrict__ w3,
    unsigned short* __restrict__ PH, unsigned short* __restrict__ PL,
    unsigned short* __restrict__ WC,
    float* __restrict__ Cr, float* __restrict__ W0)
{
    __shared__ unsigned short sH[16 * 64 * 8];   // 16 KB
    __shared__ unsigned short sL[16 * 64 * 8];   // 16 KB
    __shared__ unsigned short sW[16 * 64 * 8];   // 16 KB

    const int rt = blockIdx.x;            // rule tile 0..7
    const int t  = threadIdx.x;           // 0..511
    const int rl = t >> 4;                // rule within tile (0..31)
    const int rule = rt * 32 + rl;
    const int f0 = (t & 15) * 8;          // 8 consecutive features

    const float* mrow = mu    + (size_t)rule * NF + f0;
    const float* srow = sigma + (size_t)rule * NF + f0;
    const float* wrow = w3    + (size_t)rule * (NF + 1) + 1 + f0;

    const float4 m40 = *(const float4*)(mrow);
    const float4 m41 = *(const float4*)(mrow + 4);
    const float4 s40 = *(const float4*)(srow);
    const float4 s41 = *(const float4*)(srow + 4);
    const float mv[8] = {m40.x, m40.y, m40.z, m40.w, m41.x, m41.y, m41.z, m41.w};
    const float sv[8] = {s40.x, s40.y, s40.z, s40.w, s41.x, s41.y, s41.z, s41.w};

    const int ks   = f0 >> 4;                         // 0..7, same for all 8 f
    const int lane = ((f0 >> 3) & 1) * 32 + rl;       // same for all 8 f
    const int base1 = (ks       * 64 + lane) * 8;     // u2 / w_hi entry
    const int base2 = ((ks + 8) * 64 + lane) * 8;     // u1 / w_lo entry

    float cc = 0.f;
    #pragma unroll
    for (int j = 0; j < 8; ++j) {
        const float s  = sv[j];
        const float m  = mv[j];
        const float w  = wrow[j];
        const float u2 = -0.5f / fmaxf(s * s, 1e-30f);
        const float u1 = -2.0f * u2 * m;
        cc += u2 * m * m;

        const unsigned short u2h = f2bf(u2);
        const unsigned short u1h = f2bf(u1);
        const unsigned short wh  = f2bf(w);
        sH[base1 + j] = u2h;
        sL[base1 + j] = f2bf(u2 - bf2f(u2h));
        sW[base1 + j] = wh;
        sH[base2 + j] = u1h;
        sL[base2 + j] = f2bf(u1 - bf2f(u1h));
        sW[base2 + j] = f2bf(w - bf2f(wh));
    }

    cc += __shfl_xor(cc, 1);
    cc += __shfl_xor(cc, 2);
    cc += __shfl_xor(cc, 4);
    cc += __shfl_xor(cc, 8);
    if ((t & 15) == 0) {
        Cr[rule] = cc;
        W0[rule] = w3[(size_t)rule * (NF + 1)];
    }

    __syncthreads();

    {
        s16x8* gH = (s16x8*)PH + (size_t)rt * 1024;
        s16x8* gL = (s16x8*)PL + (size_t)rt * 1024;
        s16x8* gW = (s16x8*)WC + (size_t)rt * 1024;
        const s16x8* lH = (const s16x8*)sH;
        const s16x8* lL = (const s16x8*)sL;
        const s16x8* lW = (const s16x8*)sW;
        gH[t]       = lH[t];
        gH[t + 512] = lH[t + 512];
        gL[t]       = lL[t];
        gL[t + 512] = lL[t + 512];
        gW[t]       = lW[t];
        gW[t + 512] = lW[t + 512];
    }
}

// ---------------------------------------------------------------------------
// main v2 (r12): same math/layout as r8 (absmax-validated), rescheduled:
//  - Phase 1 (ks 0..7):  S-side d^2 frags only: 3 MFMA, 2 A-loads, 2 ds_reads
//  - Phase 2 (ks 8..15): S-side d frags + ALL of Q (WC_hi pulled from entry
//    ks-8): 6 MFMA, 4 A-loads, 2 ds_reads
//    -> B ds_reads 48->32/wave; every iter uniform.
//  - unroll x2, static-named 1-pair-deep prefetch of A (global) AND B (LDS):
//    loads for pair p+1 issue before pair p's MFMAs (hides 120cy LDS /
//    ~300cy L2 latency under MFMA issue; bounded regs, no dynamic indexing).
//  - 5 accumulators (S0,S1,S2,Q0,Q1): no >2-deep same-acc MFMA chains.
// Epilogue: rule=exp(min(S+Cr,0))-28; 16-reg reduce; shfl_xor 32; LDS combine.
// C/D layout (HW-verified): col=lane&31, row=(reg&3)+8*(reg>>2)+4*(lane>>5)
// ---------------------------------------------------------------------------
__global__ __launch_bounds__(512) void fnn_mfma(
    const float* __restrict__ data,
    const unsigned short* __restrict__ PH, const unsigned short* __restrict__ PL,
    const unsigned short* __restrict__ WC,
    const float* __restrict__ Cr, const float* __restrict__ W0,
    float* __restrict__ out)
{
    __shared__ s16x8 sBH[16][64], sBL[16][64];   // 32 KB
    __shared__ float sCr[NR], sW0[NR];
    __shared__ float redD[8][BCOLS], redN[8][BCOLS];

    const int tid = threadIdx.x;
    if (tid < NR) sCr[tid] = Cr[tid];
    else          sW0[tid - NR] = W0[tid - NR];

    const int b0 = blockIdx.x * BCOLS;

    // ---- cooperative B build: thread (bks,bln) -> 4 LDS entries
    {
        const int bks = tid >> 6;        // 0..7
        const int bln = tid & 63;
        const float* p = data + (size_t)(b0 + (bln & 31)) * NF
                              + bks * 16 + (bln >> 5) * 8;
        const float4 v0 = *(const float4*)(p);
        const float4 v1 = *(const float4*)(p + 4);
        const float dv[8] = {v0.x, v0.y, v0.z, v0.w, v1.x, v1.y, v1.z, v1.w};
        s16x8 e_d, e_dl, e_d2, e_d2l;
        #pragma unroll
        for (int j = 0; j < 8; ++j) {
            const float d  = dv[j];
            const float d2 = d * d;
            const unsigned short dh  = f2bf(d);
            const unsigned short d2h = f2bf(d2);
            e_d  [j] = (short)dh;
            e_dl [j] = (short)f2bf(d  - bf2f(dh));
            e_d2 [j] = (short)d2h;
            e_d2l[j] = (short)f2bf(d2 - bf2f(d2h));
        }
        sBH[bks    ][bln] = e_d2;   // ks<8  : d^2 hi
        sBL[bks    ][bln] = e_d2l;  // ks<8  : d^2 lo
        sBH[bks + 8][bln] = e_d;    // ks>=8 : d hi
        sBL[bks + 8][bln] = e_dl;   // ks>=8 : d lo
    }
    __syncthreads();

    const int wv   = tid >> 6;     // wave id == rule tile
    const int lane = tid & 63;
    const int col  = lane & 31;
    const int half = lane >> 5;

    const s16x8* PHp = (const s16x8*)PH + (size_t)wv * 16 * 64 + lane;
    const s16x8* PLp = (const s16x8*)PL + (size_t)wv * 16 * 64 + lane;
    const s16x8* WCp = (const s16x8*)WC + (size_t)wv * 16 * 64 + lane;

    f32x16 accS0, accS1, accS2, accQ0, accQ1;
    #pragma unroll
    for (int e = 0; e < 16; ++e) {
        accS0[e] = 0.f; accS1[e] = 0.f; accS2[e] = 0.f;
        accQ0[e] = 0.f; accQ1[e] = 0.f;
    }

    // ================= Phase 1: ks = 0..7 (d^2 frags) =================
    {
        s16x8 a0e = PHp[0],       a1e = PLp[0];
        s16x8 a0o = PHp[64],      a1o = PLp[64];
        s16x8 bhe = sBH[0][lane], ble = sBL[0][lane];
        s16x8 bho = sBH[1][lane], blo = sBL[1][lane];

        #pragma unroll 1
        for (int p = 0; p < 4; ++p) {
            const int k2 = (p < 3) ? (2 * p + 2) : 6;   // clamp (redundant last)
            // prefetch pair p+1 (A from global, B from LDS) BEFORE MFMAs
            const s16x8 n0e = PHp[k2 * 64],        n1e = PLp[k2 * 64];
            const s16x8 n0o = PHp[(k2 + 1) * 64],  n1o = PLp[(k2 + 1) * 64];
            const s16x8 nbe = sBH[k2][lane],       nle = sBL[k2][lane];
            const s16x8 nbo = sBH[k2 + 1][lane],   nlo = sBL[k2 + 1][lane];

            accS0 = mfma_bf16(a0e, bhe, accS0);   // u2_hi . d2_hi
            accS1 = mfma_bf16(a1e, bhe, accS1);   // u2_lo . d2_hi
            accS2 = mfma_bf16(a0e, ble, accS2);   // u2_hi . d2_lo
            accS0 = mfma_bf16(a0o, bho, accS0);
            accS1 = mfma_bf16(a1o, bho, accS1);
            accS2 = mfma_bf16(a0o, blo, accS2);

            a0e = n0e; a1e = n1e; a0o = n0o; a1o = n1o;
            bhe = nbe; ble = nle; bho = nbo; blo = nlo;
        }
    }

    // ========== Phase 2: ks = 8..15 (d frags, S + all of Q) ==========
    {
        s16x8 a0e = PHp[8 * 64],  a1e = PLp[8 * 64];
        s16x8 whe = WCp[0],       wle = WCp[8 * 64];
        s16x8 a0o = PHp[9 * 64],  a1o = PLp[9 * 64];
        s16x8 who = WCp[64],      wlo_ = WCp[9 * 64];
        s16x8 bhe = sBH[8][lane], ble = sBL[8][lane];
        s16x8 bho = sBH[9][lane], blo = sBL[9][lane];

        #pragma unroll 1
        for (int p = 0; p < 4; ++p) {
            const int k2 = (p < 3) ? (2 * p + 2) : 6;   // clamp (redundant last)
            const s16x8 n0e = PHp[(8 + k2) * 64], n1e = PLp[(8 + k2) * 64];
            const s16x8 nwe = WCp[k2 * 64],       nve = WCp[(8 + k2) * 64];
            const s16x8 n0o = PHp[(9 + k2) * 64], n1o = PLp[(9 + k2) * 64];
            const s16x8 nwo = WCp[(k2 + 1) * 64], nvo = WCp[(9 + k2) * 64];
            const s16x8 nbe = sBH[8 + k2][lane],  nle = sBL[8 + k2][lane];
            const s16x8 nbo = sBH[9 + k2][lane],  nlo = sBL[9 + k2][lane];

            accS0 = mfma_bf16(a0e, bhe, accS0);   // u1_hi . d_hi
            accS1 = mfma_bf16(a1e, bhe, accS1);   // u1_lo . d_hi
            accS2 = mfma_bf16(a0e, ble, accS2);   // u1_hi . d_lo
            accQ0 = mfma_bf16(whe, bhe, accQ0);   // w_hi . d_hi
            accQ1 = mfma_bf16(whe, ble, accQ1);   // w_hi . d_lo
            accQ1 = mfma_bf16(wle, bhe, accQ1);   // w_lo . d_hi

            accS0 = mfma_bf16(a0o, bho, accS0);
            accS1 = mfma_bf16(a1o, bho, accS1);
            accS2 = mfma_bf16(a0o, blo, accS2);
            accQ0 = mfma_bf16(who, bho, accQ0);
            accQ1 = mfma_bf16(who, blo, accQ1);
            accQ1 = mfma_bf16(wlo_, bho, accQ1);

            a0e = n0e; a1e = n1e; whe = nwe; wle = nve;
            a0o = n0o; a1o = n1o; who = nwo; wlo_ = nvo;
            bhe = nbe; ble = nle; bho = nbo; blo = nlo;
        }
    }

    float den_p = 0.f, num_p = 0.f;
    #pragma unroll
    for (int reg = 0; reg < 16; ++reg) {
        const int rloc = (reg & 3) + 8 * (reg >> 2) + 4 * half;
        const int rule = wv * 32 + rloc;
        const float S  = accS0[reg] + accS1[reg] + accS2[reg] + sCr[rule];
        const float rv = __expf(fminf(S, 0.f)) - 28.0f;   // RULE_OFFSET (10 ^ -18 == -28)
        const float cq = accQ0[reg] + accQ1[reg] + sW0[rule];
        den_p += rv;
        num_p += rv * cq;
    }
    den_p += __shfl_xor(den_p, 32);
    num_p += __shfl_xor(num_p, 32);
    if (half == 0) { redD[wv][col] = den_p; redN[wv][col] = num_p; }
    __syncthreads();

    if (tid < BCOLS) {
        float den = 0.f, num = 0.f;
        #pragma unroll
        for (int w = 0; w < 8; ++w) { den += redD[w][tid]; num += redN[w][tid]; }
        out[b0 + tid] = 1.0f / (1.0f + __expf(-(num / den)));
    }
}

// ---------------------------------------------------------------------------
// fallback (ws too small): fused f32 version (round-2 structure, known-good).
// ---------------------------------------------------------------------------
#define TBF 8
__global__ __launch_bounds__(256) void fnn_fused(
    const float* __restrict__ data,
    const float* __restrict__ mu, const float* __restrict__ sigma,
    const float* __restrict__ w3,
    float* __restrict__ out)
{
    __shared__ float d_tile[TBF][NF];
    __shared__ float red[TBF][2][4];

    const int tid = threadIdx.x;
    const int b0  = blockIdx.x * TBF;
    {
        const float4* src = (const float4*)(data + (size_t)b0 * NF);
        ((float4*)(&d_tile[0][0]))[tid] = src[tid];
    }
    __syncthreads();

    const float* mu_r = mu    + (size_t)tid * NF;
    const float* sg_r = sigma + (size_t)tid * NF;
    const float* w_r  = w3    + (size_t)tid * (NF + 1);

    float S[TBF], Q[TBF];
    #pragma unroll
    for (int b = 0; b < TBF; ++b) { S[b] = 0.f; Q[b] = 0.f; }

    #pragma unroll 2
    for (int f = 0; f < NF; f += 4) {
        const float4 m4 = *(const float4*)(mu_r + f);
        const float4 s4 = *(const float4*)(sg_r + f);
        const float w0 = w_r[1 + f + 0], w1 = w_r[1 + f + 1];
        const float w2 = w_r[1 + f + 2], w3v = w_r[1 + f + 3];
        float4 c4;
        c4.x = -0.5f / fmaxf(s4.x * s4.x, 1e-30f);
        c4.y = -0.5f / fmaxf(s4.y * s4.y, 1e-30f);
        c4.z = -0.5f / fmaxf(s4.z * s4.z, 1e-30f);
        c4.w = -0.5f / fmaxf(s4.w * s4.w, 1e-30f);
        #pragma unroll
        for (int b = 0; b < TBF; ++b) {
            const float4 d4 = *(const float4*)(&d_tile[b][f]);
            float t;
            t = d4.x - m4.x; S[b] = fmaf(t * t, c4.x, S[b]); Q[b] = fmaf(d4.x, w0,  Q[b]);
            t = d4.y - m4.y; S[b] = fmaf(t * t, c4.y, S[b]); Q[b] = fmaf(d4.y, w1,  Q[b]);
            t = d4.z - m4.z; S[b] = fmaf(t * t, c4.z, S[b]); Q[b] = fmaf(d4.z, w2,  Q[b]);
            t = d4.w - m4.w; S[b] = fmaf(t * t, c4.w, S[b]); Q[b] = fmaf(d4.w, w3v, Q[b]);
        }
    }

    const float bias = w_r[0];
    #pragma unroll
    for (int b = 0; b < TBF; ++b) {
        float rule = __expf(S[b]) - 28.0f;
        float rc   = rule * (bias + Q[b]);
        #pragma unroll
        for (int off = 32; off > 0; off >>= 1) {
            rule += __shfl_down(rule, off);
            rc   += __shfl_down(rc,   off);
        }
        if ((tid & 63) == 0) {
            red[b][0][tid >> 6] = rule;
            red[b][1][tid >> 6] = rc;
        }
    }
    __syncthreads();
    if (tid < TBF) {
        const float den = red[tid][0][0] + red[tid][0][1] + red[tid][0][2] + red[tid][0][3];
        const float num = red[tid][1][0] + red[tid][1][1] + red[tid][1][2] + red[tid][1][3];
        out[b0 + tid] = 1.0f / (1.0f + __expf(-(num / den)));
    }
}

extern "C" void kernel_launch(void* const* d_in, const int* in_sizes, int n_in,
                              void* d_out, int out_size, void* d_ws, size_t ws_size,
                              hipStream_t stream) {
    const float* data  = (const float*)d_in[0];
    const float* mu    = (const float*)d_in[1];
    const float* sigma = (const float*)d_in[2];
    const float* w3    = (const float*)d_in[3];
    float* out = (float*)d_out;

    const int batch = in_sizes[0] / NF;   // 8192
    // PH + PL + WC (3 x 64K bf16 = 3 x 128 KiB) + Cr + W0 = 395,264 B
    const size_t need = 3u * 65536u * sizeof(unsigned short) + 2u * NR * sizeof(float);

    if (ws_size >= need && (batch % BCOLS) == 0) {
        unsigned short* PH = (unsigned short*)d_ws;
        unsigned short* PL = PH + 65536;
        unsigned short* WC = PL + 65536;
        float* Cr = (float*)(WC + 65536);
        float* W0 = Cr + NR;
        prep3_kernel<<<8, 512, 0, stream>>>(mu, sigma, w3, PH, PL, WC, Cr, W0);
        fnn_mfma<<<batch / BCOLS, 512, 0, stream>>>(data, PH, PL, WC, Cr, W0, out);
    } else {
        fnn_fused<<<batch / TBF, 256, 0, stream>>>(data, mu, sigma, w3, out);
    }
}

// Round 13
// 18.265 us; speedup vs baseline: 1.3990x; 1.1397x over previous
//
#include <hip/hip_runtime.h>
#include <math.h>

#define NR 256   // rules
#define NF 128   // features
#define BCOLS 32 // batch columns per block (MFMA N)

typedef short  s16x8  __attribute__((ext_vector_type(8)));   // 8 bf16 bit patterns
typedef __bf16 bf16x8 __attribute__((ext_vector_type(8)));
typedef float  f32x16 __attribute__((ext_vector_type(16)));  // MFMA 32x32 acc

__device__ __forceinline__ unsigned short f2bf(float x) {
    unsigned int u = __float_as_uint(x);
    unsigned int r = (u + 0x7FFFu + ((u >> 16) & 1u)) >> 16;  // RNE
    return (unsigned short)r;
}
__device__ __forceinline__ float bf2f(unsigned short b) {
    return __uint_as_float(((unsigned int)b) << 16);
}
__device__ __forceinline__ bf16x8 as_bf(s16x8 v) {
    return __builtin_bit_cast(bf16x8, v);
}
__device__ __forceinline__ f32x16 mfma_bf16(s16x8 a, s16x8 b, f32x16 acc) {
    return __builtin_amdgcn_mfma_f32_32x32x16_bf16(as_bf(a), as_bf(b), acc, 0, 0, 0);
}

// ---------------------------------------------------------------------------
// prep2 (verbatim r9 — the PARALLEL + COALESCED-STORE prep, validated there):
// 40 blocks x 256 thr. Blocks 0..31: thread t -> (entry e, lane); computes 8
// consecutive features' params, writes three 16B coalesced stores.
//   e=rt*16+ks2; ks2<8 -> u2_hi/u2_lo/w_hi ; ks2>=8 -> u1_hi/u1_lo/w_lo
//   rule = rt*32+(lane&31); f = (ks2&7)*16 + (lane>>5)*8 + j
// Blocks 32..39: Cr[r] = sum_f u2*mu^2 (float4 reads, 8-lane shfl), W0[r].
// r12-r13 accounting: r8 scatter-prep ~11us (2B RMW stores), prep3 ~11.5us
// (8 blocks = latency-bound). prep2 is the design with both parallelism and
// coalescing.
// ---------------------------------------------------------------------------
__global__ __launch_bounds__(256) void prep2_kernel(
    const float* __restrict__ mu, const float* __restrict__ sigma,
    const float* __restrict__ w3,
    unsigned short* __restrict__ PH, unsigned short* __restrict__ PL,
    unsigned short* __restrict__ WC,
    float* __restrict__ Cr, float* __restrict__ W0)
{
    const int blk = blockIdx.x;
    if (blk < 32) {
        const int t    = blk * 256 + threadIdx.x;   // 0..8191
        const int e    = t >> 6;                     // entry 0..127
        const int lane = t & 63;
        const int rt   = e >> 4;
        const int ks2  = e & 15;
        const bool second = (ks2 >= 8);
        const int fb   = (ks2 & 7) * 16 + (lane >> 5) * 8;
        const int rule = rt * 32 + (lane & 31);

        const float* mrow = mu    + (size_t)rule * NF + fb;
        const float* srow = sigma + (size_t)rule * NF + fb;
        const float* wrow = w3    + (size_t)rule * (NF + 1) + 1 + fb;

        s16x8 vh, vl, vw;
        #pragma unroll
        for (int j = 0; j < 8; ++j) {
            const float s  = srow[j];
            const float m  = mrow[j];
            const float w  = wrow[j];
            const float u2 = -0.5f / fmaxf(s * s, 1e-30f);
            const float val = second ? (-2.0f * u2 * m) : u2;
            const unsigned short hh = f2bf(val);
            vh[j] = (short)hh;
            vl[j] = (short)f2bf(val - bf2f(hh));
            const unsigned short wh = f2bf(w);
            vw[j] = (short)(second ? f2bf(w - bf2f(wh)) : wh);
        }
        ((s16x8*)PH)[t] = vh;   // t == e*64 + lane : fully coalesced 16B
        ((s16x8*)PL)[t] = vl;
        ((s16x8*)WC)[t] = vw;
    } else {
        const int rg   = blk - 32;                  // rule group of 32
        const int rl   = threadIdx.x >> 3;
        const int jj   = threadIdx.x & 7;
        const int rule = rg * 32 + rl;
        const float* mrow = mu    + (size_t)rule * NF + jj * 16;
        const float* srow = sigma + (size_t)rule * NF + jj * 16;
        float cc = 0.f;
        #pragma unroll
        for (int q = 0; q < 16; q += 4) {
            const float4 s4 = *(const float4*)(srow + q);
            const float4 m4 = *(const float4*)(mrow + q);
            cc += (-0.5f / fmaxf(s4.x * s4.x, 1e-30f)) * m4.x * m4.x;
            cc += (-0.5f / fmaxf(s4.y * s4.y, 1e-30f)) * m4.y * m4.y;
            cc += (-0.5f / fmaxf(s4.z * s4.z, 1e-30f)) * m4.z * m4.z;
            cc += (-0.5f / fmaxf(s4.w * s4.w, 1e-30f)) * m4.w * m4.w;
        }
        cc += __shfl_down(cc, 4);
        cc += __shfl_down(cc, 2);
        cc += __shfl_down(cc, 1);
        if (jj == 0) {
            Cr[rule] = cc;
            W0[rule] = w3[(size_t)rule * (NF + 1)];
        }
    }
}

// ---------------------------------------------------------------------------
// main (VERBATIM r8 — the best-measured main, ~6.8us warm per r11 probe).
// ---------------------------------------------------------------------------
__global__ __launch_bounds__(512) void fnn_mfma(
    const float* __restrict__ data,
    const unsigned short* __restrict__ PH, const unsigned short* __restrict__ PL,
    const unsigned short* __restrict__ WC,
    const float* __restrict__ Cr, const float* __restrict__ W0,
    float* __restrict__ out)
{
    __shared__ s16x8 sBH[16][64], sBL[16][64];   // 32 KB
    __shared__ float sCr[NR], sW0[NR];
    __shared__ float redD[8][BCOLS], redN[8][BCOLS];

    const int tid = threadIdx.x;
    if (tid < NR) sCr[tid] = Cr[tid];
    else          sW0[tid - NR] = W0[tid - NR];

    const int b0 = blockIdx.x * BCOLS;

    // ---- cooperative B build: thread (bks,bln) -> 4 LDS entries
    {
        const int bks = tid >> 6;        // 0..7
        const int bln = tid & 63;
        const float* p = data + (size_t)(b0 + (bln & 31)) * NF
                              + bks * 16 + (bln >> 5) * 8;
        const float4 v0 = *(const float4*)(p);
        const float4 v1 = *(const float4*)(p + 4);
        const float dv[8] = {v0.x, v0.y, v0.z, v0.w, v1.x, v1.y, v1.z, v1.w};
        s16x8 e_d, e_dl, e_d2, e_d2l;
        #pragma unroll
        for (int j = 0; j < 8; ++j) {
            const float d  = dv[j];
            const float d2 = d * d;
            const unsigned short dh  = f2bf(d);
            const unsigned short d2h = f2bf(d2);
            e_d  [j] = (short)dh;
            e_dl [j] = (short)f2bf(d  - bf2f(dh));
            e_d2 [j] = (short)d2h;
            e_d2l[j] = (short)f2bf(d2 - bf2f(d2h));
        }
        sBH[bks    ][bln] = e_d2;   // ks<8  : d^2 hi
        sBL[bks    ][bln] = e_d2l;  // ks<8  : d^2 lo
        sBH[bks + 8][bln] = e_d;    // ks>=8 : d hi
        sBL[bks + 8][bln] = e_dl;   // ks>=8 : d lo
    }
    __syncthreads();

    const int wv   = tid >> 6;     // wave id == rule tile
    const int lane = tid & 63;
    const int col  = lane & 31;
    const int half = lane >> 5;

    const s16x8* PHp = (const s16x8*)PH + (size_t)wv * 16 * 64 + lane;
    const s16x8* PLp = (const s16x8*)PL + (size_t)wv * 16 * 64 + lane;
    const s16x8* WCp = (const s16x8*)WC + (size_t)wv * 16 * 64 + lane;

    f32x16 accS0, accS1, accQ;
    #pragma unroll
    for (int e = 0; e < 16; ++e) { accS0[e] = 0.f; accS1[e] = 0.f; accQ[e] = 0.f; }

    s16x8 a0 = PHp[0], a1 = PLp[0], a2 = WCp[0];
    #pragma unroll 1
    for (int ks = 0; ks < 16; ++ks) {
        // strict 1-deep prefetch (clamped index keeps it branchless & bounded)
        const int nofs = ((ks < 15) ? (ks + 1) : ks) * 64;
        const s16x8 n0 = PHp[nofs];
        const s16x8 n1 = PLp[nofs];
        const s16x8 n2 = WCp[nofs];

        const s16x8 bh = sBH[ks][lane];
        const s16x8 bl = sBL[ks][lane];
        accS0 = mfma_bf16(a0, bh, accS0);   // PH . {d2h|dh}
        accS1 = mfma_bf16(a1, bh, accS1);   // PL . {d2h|dh}
        accS1 = mfma_bf16(a0, bl, accS1);   // PH . {d2l|dl}
        if (ks < 8) {                        // uniform branch
            accQ = mfma_bf16(a2, sBH[ks + 8][lane], accQ);  // w_hi . dh
            accQ = mfma_bf16(a2, sBL[ks + 8][lane], accQ);  // w_hi . dl
        } else {
            accQ = mfma_bf16(a2, bh, accQ);                 // w_lo . dh
        }
        a0 = n0; a1 = n1; a2 = n2;
    }

    float den_p = 0.f, num_p = 0.f;
    #pragma unroll
    for (int reg = 0; reg < 16; ++reg) {
        const int rloc = (reg & 3) + 8 * (reg >> 2) + 4 * half;
        const int rule = wv * 32 + rloc;
        const float S  = accS0[reg] + accS1[reg] + sCr[rule];
        const float rv = __expf(fminf(S, 0.f)) - 28.0f;   // RULE_OFFSET (10 ^ -18 == -28)
        const float cq = accQ[reg] + sW0[rule];
        den_p += rv;
        num_p += rv * cq;
    }
    den_p += __shfl_xor(den_p, 32);
    num_p += __shfl_xor(num_p, 32);
    if (half == 0) { redD[wv][col] = den_p; redN[wv][col] = num_p; }
    __syncthreads();

    if (tid < BCOLS) {
        float den = 0.f, num = 0.f;
        #pragma unroll
        for (int w = 0; w < 8; ++w) { den += redD[w][tid]; num += redN[w][tid]; }
        out[b0 + tid] = 1.0f / (1.0f + __expf(-(num / den)));
    }
}

// ---------------------------------------------------------------------------
// fallback (ws too small): fused f32 version (round-2 structure, known-good).
// ---------------------------------------------------------------------------
#define TBF 8
__global__ __launch_bounds__(256) void fnn_fused(
    const float* __restrict__ data,
    const float* __restrict__ mu, const float* __restrict__ sigma,
    const float* __restrict__ w3,
    float* __restrict__ out)
{
    __shared__ float d_tile[TBF][NF];
    __shared__ float red[TBF][2][4];

    const int tid = threadIdx.x;
    const int b0  = blockIdx.x * TBF;
    {
        const float4* src = (const float4*)(data + (size_t)b0 * NF);
        ((float4*)(&d_tile[0][0]))[tid] = src[tid];
    }
    __syncthreads();

    const float* mu_r = mu    + (size_t)tid * NF;
    const float* sg_r = sigma + (size_t)tid * NF;
    const float* w_r  = w3    + (size_t)tid * (NF + 1);

    float S[TBF], Q[TBF];
    #pragma unroll
    for (int b = 0; b < TBF; ++b) { S[b] = 0.f; Q[b] = 0.f; }

    #pragma unroll 2
    for (int f = 0; f < NF; f += 4) {
        const float4 m4 = *(const float4*)(mu_r + f);
        const float4 s4 = *(const float4*)(sg_r + f);
        const float w0 = w_r[1 + f + 0], w1 = w_r[1 + f + 1];
        const float w2 = w_r[1 + f + 2], w3v = w_r[1 + f + 3];
        float4 c4;
        c4.x = -0.5f / fmaxf(s4.x * s4.x, 1e-30f);
        c4.y = -0.5f / fmaxf(s4.y * s4.y, 1e-30f);
        c4.z = -0.5f / fmaxf(s4.z * s4.z, 1e-30f);
        c4.w = -0.5f / fmaxf(s4.w * s4.w, 1e-30f);
        #pragma unroll
        for (int b = 0; b < TBF; ++b) {
            const float4 d4 = *(const float4*)(&d_tile[b][f]);
            float t;
            t = d4.x - m4.x; S[b] = fmaf(t * t, c4.x, S[b]); Q[b] = fmaf(d4.x, w0,  Q[b]);
            t = d4.y - m4.y; S[b] = fmaf(t * t, c4.y, S[b]); Q[b] = fmaf(d4.y, w1,  Q[b]);
            t = d4.z - m4.z; S[b] = fmaf(t * t, c4.z, S[b]); Q[b] = fmaf(d4.z, w2,  Q[b]);
            t = d4.w - m4.w; S[b] = fmaf(t * t, c4.w, S[b]); Q[b] = fmaf(d4.w, w3v, Q[b]);
        }
    }

    const float bias = w_r[0];
    #pragma unroll
    for (int b = 0; b < TBF; ++b) {
        float rule = __expf(S[b]) - 28.0f;
        float rc   = rule * (bias + Q[b]);
        #pragma unroll
        for (int off = 32; off > 0; off >>= 1) {
            rule += __shfl_down(rule, off);
            rc   += __shfl_down(rc,   off);
        }
        if ((tid & 63) == 0) {
            red[b][0][tid >> 6] = rule;
            red[b][1][tid >> 6] = rc;
        }
    }
    __syncthreads();
    if (tid < TBF) {
        const float den = red[tid][0][0] + red[tid][0][1] + red[tid][0][2] + red[tid][0][3];
        const float num = red[tid][1][0] + red[tid][1][1] + red[tid][1][2] + red[tid][1][3];
        out[b0 + tid] = 1.0f / (1.0f + __expf(-(num / den)));
    }
}

extern "C" void kernel_launch(void* const* d_in, const int* in_sizes, int n_in,
                              void* d_out, int out_size, void* d_ws, size_t ws_size,
                              hipStream_t stream) {
    const float* data  = (const float*)d_in[0];
    const float* mu    = (const float*)d_in[1];
    const float* sigma = (const float*)d_in[2];
    const float* w3    = (const float*)d_in[3];
    float* out = (float*)d_out;

    const int batch = in_sizes[0] / NF;   // 8192
    // PH + PL + WC (3 x 64K bf16 = 3 x 128 KiB) + Cr + W0 = 395,264 B
    const size_t need = 3u * 65536u * sizeof(unsigned short) + 2u * NR * sizeof(float);

    if (ws_size >= need && (batch % BCOLS) == 0) {
        unsigned short* PH = (unsigned short*)d_ws;
        unsigned short* PL = PH + 65536;
        unsigned short* WC = PL + 65536;
        float* Cr = (float*)(WC + 65536);
        float* W0 = Cr + NR;
        prep2_kernel<<<40, 256, 0, stream>>>(mu, sigma, w3, PH, PL, WC, Cr, W0);
        fnn_mfma<<<batch / BCOLS, 512, 0, stream>>>(data, PH, PL, WC, Cr, W0, out);
    } else {
        fnn_fused<<<batch / TBF, 256, 0, stream>>>(data, mu, sigma, w3, out);
    }
}

// Round 14
// 17.433 us; speedup vs baseline: 1.4657x; 1.0477x over previous
//
#include <hip/hip_runtime.h>
#include <math.h>

#define NR 256   // rules
#define NF 128   // features
#define BCOLS 32 // batch columns per block (MFMA N)

typedef short  s16x8  __attribute__((ext_vector_type(8)));   // 8 bf16 bit patterns
typedef __bf16 bf16x8 __attribute__((ext_vector_type(8)));
typedef float  f32x16 __attribute__((ext_vector_type(16)));  // MFMA 32x32 acc

__device__ __forceinline__ unsigned short f2bf(float x) {
    unsigned int u = __float_as_uint(x);
    unsigned int r = (u + 0x7FFFu + ((u >> 16) & 1u)) >> 16;  // RNE
    return (unsigned short)r;
}
__device__ __forceinline__ float bf2f(unsigned short b) {
    return __uint_as_float(((unsigned int)b) << 16);
}
__device__ __forceinline__ bf16x8 as_bf(s16x8 v) {
    return __builtin_bit_cast(bf16x8, v);
}
__device__ __forceinline__ f32x16 mfma_bf16(s16x8 a, s16x8 b, f32x16 acc) {
    return __builtin_amdgcn_mfma_f32_32x32x16_bf16(as_bf(a), as_bf(b), acc, 0, 0, 0);
}

// ---------------------------------------------------------------------------
// prep2 (verbatim r9/r13, validated): parallel + coalesced-store prep.
// ---------------------------------------------------------------------------
__global__ __launch_bounds__(256) void prep2_kernel(
    const float* __restrict__ mu, const float* __restrict__ sigma,
    const float* __restrict__ w3,
    unsigned short* __restrict__ PH, unsigned short* __restrict__ PL,
    unsigned short* __restrict__ WC,
    float* __restrict__ Cr, float* __restrict__ W0)
{
    const int blk = blockIdx.x;
    if (blk < 32) {
        const int t    = blk * 256 + threadIdx.x;   // 0..8191
        const int e    = t >> 6;                     // entry 0..127
        const int lane = t & 63;
        const int rt   = e >> 4;
        const int ks2  = e & 15;
        const bool second = (ks2 >= 8);
        const int fb   = (ks2 & 7) * 16 + (lane >> 5) * 8;
        const int rule = rt * 32 + (lane & 31);

        const float* mrow = mu    + (size_t)rule * NF + fb;
        const float* srow = sigma + (size_t)rule * NF + fb;
        const float* wrow = w3    + (size_t)rule * (NF + 1) + 1 + fb;

        s16x8 vh, vl, vw;
        #pragma unroll
        for (int j = 0; j < 8; ++j) {
            const float s  = srow[j];
            const float m  = mrow[j];
            const float w  = wrow[j];
            const float u2 = -0.5f / fmaxf(s * s, 1e-30f);
            const float val = second ? (-2.0f * u2 * m) : u2;
            const unsigned short hh = f2bf(val);
            vh[j] = (short)hh;
            vl[j] = (short)f2bf(val - bf2f(hh));
            const unsigned short wh = f2bf(w);
            vw[j] = (short)(second ? f2bf(w - bf2f(wh)) : wh);
        }
        ((s16x8*)PH)[t] = vh;   // t == e*64 + lane : fully coalesced 16B
        ((s16x8*)PL)[t] = vl;
        ((s16x8*)WC)[t] = vw;
    } else {
        const int rg   = blk - 32;                  // rule group of 32
        const int rl   = threadIdx.x >> 3;
        const int jj   = threadIdx.x & 7;
        const int rule = rg * 32 + rl;
        const float* mrow = mu    + (size_t)rule * NF + jj * 16;
        const float* srow = sigma + (size_t)rule * NF + jj * 16;
        float cc = 0.f;
        #pragma unroll
        for (int q = 0; q < 16; q += 4) {
            const float4 s4 = *(const float4*)(srow + q);
            const float4 m4 = *(const float4*)(mrow + q);
            cc += (-0.5f / fmaxf(s4.x * s4.x, 1e-30f)) * m4.x * m4.x;
            cc += (-0.5f / fmaxf(s4.y * s4.y, 1e-30f)) * m4.y * m4.y;
            cc += (-0.5f / fmaxf(s4.z * s4.z, 1e-30f)) * m4.z * m4.z;
            cc += (-0.5f / fmaxf(s4.w * s4.w, 1e-30f)) * m4.w * m4.w;
        }
        cc += __shfl_down(cc, 4);
        cc += __shfl_down(cc, 2);
        cc += __shfl_down(cc, 1);
        if (jj == 0) {
            Cr[rule] = cc;
            W0[rule] = w3[(size_t)rule * (NF + 1)];
        }
    }
}

// ---------------------------------------------------------------------------
// main v3 (r14): r8's math/layout VERBATIM, but the 16-ks loop is fully
// unrolled into 4 groups of 4 with TWO rotating A-register groups (X, Y):
//   load G0->X, G1->Y | MFMA X(ks0-3) | load G2->X | MFMA Y(ks4-7) |
//   load G3->Y | MFMA X(ks8-11) | MFMA Y(ks12-15)
// Prefetch distance = 4 iterations (~600cy of issue) covers the ~900cy cold
// L3/HBM miss that r8's 1-deep prefetch (~150cy) could not — r11's probe
// showed main is 16.5us cold vs 7us warm (the kernel-boundary L2 invalidate
// makes every A-load miss). sched_barrier(0) between clusters pins the
// schedule so the compiler can't hoist all loads (r7's spill trap).
// With grid=256 blocks on 256 CUs (1 block/CU), VGPR<=256 is occupancy-free:
// X(48)+Y(48)+acc(48)+temps ~ 180 VGPR, no spill.
// C/D layout (HW-verified): col=lane&31, row=(reg&3)+8*(reg>>2)+4*(lane>>5)
// ---------------------------------------------------------------------------
__global__ __launch_bounds__(512) void fnn_mfma(
    const float* __restrict__ data,
    const unsigned short* __restrict__ PH, const unsigned short* __restrict__ PL,
    const unsigned short* __restrict__ WC,
    const float* __restrict__ Cr, const float* __restrict__ W0,
    float* __restrict__ out)
{
    __shared__ s16x8 sBH[16][64], sBL[16][64];   // 32 KB
    __shared__ float sCr[NR], sW0[NR];
    __shared__ float redD[8][BCOLS], redN[8][BCOLS];

    const int tid = threadIdx.x;
    if (tid < NR) sCr[tid] = Cr[tid];
    else          sW0[tid - NR] = W0[tid - NR];

    const int b0 = blockIdx.x * BCOLS;

    // ---- cooperative B build: thread (bks,bln) -> 4 LDS entries
    {
        const int bks = tid >> 6;        // 0..7
        const int bln = tid & 63;
        const float* p = data + (size_t)(b0 + (bln & 31)) * NF
                              + bks * 16 + (bln >> 5) * 8;
        const float4 v0 = *(const float4*)(p);
        const float4 v1 = *(const float4*)(p + 4);
        const float dv[8] = {v0.x, v0.y, v0.z, v0.w, v1.x, v1.y, v1.z, v1.w};
        s16x8 e_d, e_dl, e_d2, e_d2l;
        #pragma unroll
        for (int j = 0; j < 8; ++j) {
            const float d  = dv[j];
            const float d2 = d * d;
            const unsigned short dh  = f2bf(d);
            const unsigned short d2h = f2bf(d2);
            e_d  [j] = (short)dh;
            e_dl [j] = (short)f2bf(d  - bf2f(dh));
            e_d2 [j] = (short)d2h;
            e_d2l[j] = (short)f2bf(d2 - bf2f(d2h));
        }
        sBH[bks    ][bln] = e_d2;   // ks<8  : d^2 hi
        sBL[bks    ][bln] = e_d2l;  // ks<8  : d^2 lo
        sBH[bks + 8][bln] = e_d;    // ks>=8 : d hi
        sBL[bks + 8][bln] = e_dl;   // ks>=8 : d lo
    }
    __syncthreads();

    const int wv   = tid >> 6;     // wave id == rule tile
    const int lane = tid & 63;
    const int col  = lane & 31;
    const int half = lane >> 5;

    const s16x8* PHp = (const s16x8*)PH + (size_t)wv * 16 * 64 + lane;
    const s16x8* PLp = (const s16x8*)PL + (size_t)wv * 16 * 64 + lane;
    const s16x8* WCp = (const s16x8*)WC + (size_t)wv * 16 * 64 + lane;

    f32x16 accS0, accS1, accQ;
    #pragma unroll
    for (int e = 0; e < 16; ++e) { accS0[e] = 0.f; accS1[e] = 0.f; accQ[e] = 0.f; }

    // two rotating A-register groups (12 frags = 48 VGPR each)
    s16x8 X0h, X0l, X0w, X1h, X1l, X1w, X2h, X2l, X2w, X3h, X3l, X3w;
    s16x8 Y0h, Y0l, Y0w, Y1h, Y1l, Y1w, Y2h, Y2l, Y2w, Y3h, Y3l, Y3w;

#define LOADX(G) \
    X0h = PHp[((G)*4+0)*64]; X0l = PLp[((G)*4+0)*64]; X0w = WCp[((G)*4+0)*64]; \
    X1h = PHp[((G)*4+1)*64]; X1l = PLp[((G)*4+1)*64]; X1w = WCp[((G)*4+1)*64]; \
    X2h = PHp[((G)*4+2)*64]; X2l = PLp[((G)*4+2)*64]; X2w = WCp[((G)*4+2)*64]; \
    X3h = PHp[((G)*4+3)*64]; X3l = PLp[((G)*4+3)*64]; X3w = WCp[((G)*4+3)*64];
#define LOADY(G) \
    Y0h = PHp[((G)*4+0)*64]; Y0l = PLp[((G)*4+0)*64]; Y0w = WCp[((G)*4+0)*64]; \
    Y1h = PHp[((G)*4+1)*64]; Y1l = PLp[((G)*4+1)*64]; Y1w = WCp[((G)*4+1)*64]; \
    Y2h = PHp[((G)*4+2)*64]; Y2l = PLp[((G)*4+2)*64]; Y2w = WCp[((G)*4+2)*64]; \
    Y3h = PHp[((G)*4+3)*64]; Y3l = PLp[((G)*4+3)*64]; Y3w = WCp[((G)*4+3)*64];

// ks < 8 : bh/bl are d^2 hi/lo ; Q uses d hi/lo from entries ks+8
#define KS_LO(AH, AL, AW, KS)                        \
    {                                                 \
        const s16x8 bh = sBH[KS][lane];               \
        const s16x8 bl = sBL[KS][lane];               \
        const s16x8 qh = sBH[(KS) + 8][lane];         \
        const s16x8 ql = sBL[(KS) + 8][lane];         \
        accS0 = mfma_bf16(AH, bh, accS0);             \
        accS1 = mfma_bf16(AL, bh, accS1);             \
        accS1 = mfma_bf16(AH, bl, accS1);             \
        accQ  = mfma_bf16(AW, qh, accQ);              \
        accQ  = mfma_bf16(AW, ql, accQ);              \
    }
// ks >= 8 : bh/bl are d hi/lo ; Q (w_lo) uses bh
#define KS_HI(AH, AL, AW, KS)                        \
    {                                                 \
        const s16x8 bh = sBH[KS][lane];               \
        const s16x8 bl = sBL[KS][lane];               \
        accS0 = mfma_bf16(AH, bh, accS0);             \
        accS1 = mfma_bf16(AL, bh, accS1);             \
        accS1 = mfma_bf16(AH, bl, accS1);             \
        accQ  = mfma_bf16(AW, bh, accQ);              \
    }

    LOADX(0)
    LOADY(1)
    KS_LO(X0h, X0l, X0w, 0)
    KS_LO(X1h, X1l, X1w, 1)
    KS_LO(X2h, X2l, X2w, 2)
    KS_LO(X3h, X3l, X3w, 3)
    __builtin_amdgcn_sched_barrier(0);
    LOADX(2)
    KS_LO(Y0h, Y0l, Y0w, 4)
    KS_LO(Y1h, Y1l, Y1w, 5)
    KS_LO(Y2h, Y2l, Y2w, 6)
    KS_LO(Y3h, Y3l, Y3w, 7)
    __builtin_amdgcn_sched_barrier(0);
    LOADY(3)
    KS_HI(X0h, X0l, X0w, 8)
    KS_HI(X1h, X1l, X1w, 9)
    KS_HI(X2h, X2l, X2w, 10)
    KS_HI(X3h, X3l, X3w, 11)
    __builtin_amdgcn_sched_barrier(0);
    KS_HI(Y0h, Y0l, Y0w, 12)
    KS_HI(Y1h, Y1l, Y1w, 13)
    KS_HI(Y2h, Y2l, Y2w, 14)
    KS_HI(Y3h, Y3l, Y3w, 15)

#undef LOADX
#undef LOADY
#undef KS_LO
#undef KS_HI

    float den_p = 0.f, num_p = 0.f;
    #pragma unroll
    for (int reg = 0; reg < 16; ++reg) {
        const int rloc = (reg & 3) + 8 * (reg >> 2) + 4 * half;
        const int rule = wv * 32 + rloc;
        const float S  = accS0[reg] + accS1[reg] + sCr[rule];
        const float rv = __expf(fminf(S, 0.f)) - 28.0f;   // RULE_OFFSET (10 ^ -18 == -28)
        const float cq = accQ[reg] + sW0[rule];
        den_p += rv;
        num_p += rv * cq;
    }
    den_p += __shfl_xor(den_p, 32);
    num_p += __shfl_xor(num_p, 32);
    if (half == 0) { redD[wv][col] = den_p; redN[wv][col] = num_p; }
    __syncthreads();

    if (tid < BCOLS) {
        float den = 0.f, num = 0.f;
        #pragma unroll
        for (int w = 0; w < 8; ++w) { den += redD[w][tid]; num += redN[w][tid]; }
        out[b0 + tid] = 1.0f / (1.0f + __expf(-(num / den)));
    }
}

// ---------------------------------------------------------------------------
// fallback (ws too small): fused f32 version (round-2 structure, known-good).
// ---------------------------------------------------------------------------
#define TBF 8
__global__ __launch_bounds__(256) void fnn_fused(
    const float* __restrict__ data,
    const float* __restrict__ mu, const float* __restrict__ sigma,
    const float* __restrict__ w3,
    float* __restrict__ out)
{
    __shared__ float d_tile[TBF][NF];
    __shared__ float red[TBF][2][4];

    const int tid = threadIdx.x;
    const int b0  = blockIdx.x * TBF;
    {
        const float4* src = (const float4*)(data + (size_t)b0 * NF);
        ((float4*)(&d_tile[0][0]))[tid] = src[tid];
    }
    __syncthreads();

    const float* mu_r = mu    + (size_t)tid * NF;
    const float* sg_r = sigma + (size_t)tid * NF;
    const float* w_r  = w3    + (size_t)tid * (NF + 1);

    float S[TBF], Q[TBF];
    #pragma unroll
    for (int b = 0; b < TBF; ++b) { S[b] = 0.f; Q[b] = 0.f; }

    #pragma unroll 2
    for (int f = 0; f < NF; f += 4) {
        const float4 m4 = *(const float4*)(mu_r + f);
        const float4 s4 = *(const float4*)(sg_r + f);
        const float w0 = w_r[1 + f + 0], w1 = w_r[1 + f + 1];
        const float w2 = w_r[1 + f + 2], w3v = w_r[1 + f + 3];
        float4 c4;
        c4.x = -0.5f / fmaxf(s4.x * s4.x, 1e-30f);
        c4.y = -0.5f / fmaxf(s4.y * s4.y, 1e-30f);
        c4.z = -0.5f / fmaxf(s4.z * s4.z, 1e-30f);
        c4.w = -0.5f / fmaxf(s4.w * s4.w, 1e-30f);
        #pragma unroll
        for (int b = 0; b < TBF; ++b) {
            const float4 d4 = *(const float4*)(&d_tile[b][f]);
            float t;
            t = d4.x - m4.x; S[b] = fmaf(t * t, c4.x, S[b]); Q[b] = fmaf(d4.x, w0,  Q[b]);
            t = d4.y - m4.y; S[b] = fmaf(t * t, c4.y, S[b]); Q[b] = fmaf(d4.y, w1,  Q[b]);
            t = d4.z - m4.z; S[b] = fmaf(t * t, c4.z, S[b]); Q[b] = fmaf(d4.z, w2,  Q[b]);
            t = d4.w - m4.w; S[b] = fmaf(t * t, c4.w, S[b]); Q[b] = fmaf(d4.w, w3v, Q[b]);
        }
    }

    const float bias = w_r[0];
    #pragma unroll
    for (int b = 0; b < TBF; ++b) {
        float rule = __expf(S[b]) - 28.0f;
        float rc   = rule * (bias + Q[b]);
        #pragma unroll
        for (int off = 32; off > 0; off >>= 1) {
            rule += __shfl_down(rule, off);
            rc   += __shfl_down(rc,   off);
        }
        if ((tid & 63) == 0) {
            red[b][0][tid >> 6] = rule;
            red[b][1][tid >> 6] = rc;
        }
    }
    __syncthreads();
    if (tid < TBF) {
        const float den = red[tid][0][0] + red[tid][0][1] + red[tid][0][2] + red[tid][0][3];
        const float num = red[tid][1][0] + red[tid][1][1] + red[tid][1][2] + red[tid][1][3];
        out[b0 + tid] = 1.0f / (1.0f + __expf(-(num / den)));
    }
}

extern "C" void kernel_launch(void* const* d_in, const int* in_sizes, int n_in,
                              void* d_out, int out_size, void* d_ws, size_t ws_size,
                              hipStream_t stream) {
    const float* data  = (const float*)d_in[0];
    const float* mu    = (const float*)d_in[1];
    const float* sigma = (const float*)d_in[2];
    const float* w3    = (const float*)d_in[3];
    float* out = (float*)d_out;

    const int batch = in_sizes[0] / NF;   // 8192
    // PH + PL + WC (3 x 64K bf16 = 3 x 128 KiB) + Cr + W0 = 395,264 B
    const size_t need = 3u * 65536u * sizeof(unsigned short) + 2u * NR * sizeof(float);

    if (ws_size >= need && (batch % BCOLS) == 0) {
        unsigned short* PH = (unsigned short*)d_ws;
        unsigned short* PL = PH + 65536;
        unsigned short* WC = PL + 65536;
        float* Cr = (float*)(WC + 65536);
        float* W0 = Cr + NR;
        prep2_kernel<<<40, 256, 0, stream>>>(mu, sigma, w3, PH, PL, WC, Cr, W0);
        fnn_mfma<<<batch / BCOLS, 512, 0, stream>>>(data, PH, PL, WC, Cr, W0, out);
    } else {
        fnn_fused<<<batch / TBF, 256, 0, stream>>>(data, mu, sigma, w3, out);
    }
}